// Round 2
// baseline (209.443 us; speedup 1.0000x reference)
//
#include <hip/hip_runtime.h>

#define NSTEP 64
#define HDIM 1024
#define BDIM 2048
#define OHH 511

__device__ __forceinline__ float bf2f(unsigned short u) {
    return __uint_as_float(((unsigned int)u) << 16);
}
__device__ __forceinline__ unsigned short f2bf(float f) {
    unsigned int u = __float_as_uint(f);
    unsigned int r = (u + 0x7fffu + ((u >> 16) & 1u)) >> 16;  // RNE
    return (unsigned short)r;
}

// ---------------------------------------------------------------------------
// Kernel 0: detect input dtype. For bf16 N(0,1) data, even-position 16-bit
// words are genuine bf16 -> exponent field in [0x60,0x82] essentially always.
// For f32 data, even-position words are low mantissa halves -> random
// exponents, ~14% in band. flag: 0 = bf16, 1 = f32. Deterministic per input.
// ---------------------------------------------------------------------------
__global__ void detect_kernel(const unsigned short* __restrict__ x, int* flag) {
    if (threadIdx.x == 0) {
        int cnt = 0;
        for (int i = 0; i < 64; i += 2) {
            unsigned int e = (x[i] >> 7) & 0xFFu;
            if (e >= 0x60u && e <= 0x82u) cnt++;
        }
        *flag = (cnt >= 24) ? 0 : 1;
    }
}

// ---------------------------------------------------------------------------
// Kernel 1: precompute (cos th, sin th, sin phi, cos phi) tables + omega table
// etab[64][512], otab[64][512] (slot 511 = identity), wtab[1024]
// ---------------------------------------------------------------------------
__global__ void coeff_kernel(const void* __restrict__ omega,
                             const void* __restrict__ ETh,
                             const void* __restrict__ OTh,
                             const void* __restrict__ EPh,
                             const void* __restrict__ OPh,
                             float4* __restrict__ etab,
                             float4* __restrict__ otab,
                             float2* __restrict__ wtab,
                             const int* __restrict__ flagp)
{
    const int isf32 = *flagp;
    int idx = blockIdx.x * 256 + threadIdx.x;
    if (idx < NSTEP * 512) {
        float th = isf32 ? ((const float*)ETh)[idx] : bf2f(((const unsigned short*)ETh)[idx]);
        float ph = isf32 ? ((const float*)EPh)[idx] : bf2f(((const unsigned short*)EPh)[idx]);
        float c, s, cp, sp;
        sincosf(th, &s, &c);
        sincosf(ph, &sp, &cp);
        etab[idx] = make_float4(c, s, sp, cp);
    } else if (idx < 2 * NSTEP * 512) {
        int i = idx - NSTEP * 512;
        int l = i >> 9;
        int j = i & 511;
        float4 v;
        if (j < OHH) {
            float th = isf32 ? ((const float*)OTh)[l * OHH + j] : bf2f(((const unsigned short*)OTh)[l * OHH + j]);
            float ph = isf32 ? ((const float*)OPh)[l * OHH + j] : bf2f(((const unsigned short*)OPh)[l * OHH + j]);
            float c, s, cp, sp;
            sincosf(th, &s, &c);
            sincosf(ph, &sp, &cp);
            v = make_float4(c, s, sp, cp);
        } else {
            v = make_float4(1.f, 0.f, 1.f, 0.f);  // identity rotation
        }
        otab[i] = v;
    } else if (idx < 2 * NSTEP * 512 + HDIM) {
        int c = idx - 2 * NSTEP * 512;
        float w = isf32 ? ((const float*)omega)[c] : bf2f(((const unsigned short*)omega)[c]);
        float cw, sw;
        sincosf(w, &sw, &cw);
        wtab[c] = make_float2(cw, sw);
    }
}

// ---------------------------------------------------------------------------
// Kernel 2: one wave = 2 rows; lane owns 16 consecutive columns in registers.
// Even pairs lane-internal; odd pairs: 7 internal + 2 boundary via shfl with
// redundant boundary-pair compute (no write-back shuffle needed).
// ---------------------------------------------------------------------------
__global__ __launch_bounds__(256) void eunn_kernel(
    const void* __restrict__ x_re,
    const void* __restrict__ x_im,
    const float4* __restrict__ etab,
    const float4* __restrict__ otab,
    const float2* __restrict__ wtab,
    void* __restrict__ out,
    const int* __restrict__ flagp)
{
    const int isf32 = *flagp;
    const int lane = threadIdx.x & 63;
    const int wave = threadIdx.x >> 6;
    const int row0 = blockIdx.x * 8 + wave * 2;
    const int colbase = lane << 4;

    float xr[2][16], xi[2][16];

    // --- load state -> f32 registers ---
    if (isf32) {
        #pragma unroll
        for (int r = 0; r < 2; ++r) {
            const float* pr = (const float*)x_re + (row0 + r) * HDIM + colbase;
            const float* pi = (const float*)x_im + (row0 + r) * HDIM + colbase;
            #pragma unroll
            for (int q = 0; q < 4; ++q) {
                float4 vr = reinterpret_cast<const float4*>(pr)[q];
                float4 vi = reinterpret_cast<const float4*>(pi)[q];
                xr[r][4*q] = vr.x; xr[r][4*q+1] = vr.y; xr[r][4*q+2] = vr.z; xr[r][4*q+3] = vr.w;
                xi[r][4*q] = vi.x; xi[r][4*q+1] = vi.y; xi[r][4*q+2] = vi.z; xi[r][4*q+3] = vi.w;
            }
        }
    } else {
        #pragma unroll
        for (int r = 0; r < 2; ++r) {
            const unsigned short* pr = (const unsigned short*)x_re + (row0 + r) * HDIM + colbase;
            const unsigned short* pi = (const unsigned short*)x_im + (row0 + r) * HDIM + colbase;
            #pragma unroll
            for (int h = 0; h < 2; ++h) {
                uint4 ur = *reinterpret_cast<const uint4*>(pr + 8 * h);
                uint4 ui = *reinterpret_cast<const uint4*>(pi + 8 * h);
                unsigned int wr[4] = {ur.x, ur.y, ur.z, ur.w};
                unsigned int wi[4] = {ui.x, ui.y, ui.z, ui.w};
                #pragma unroll
                for (int q = 0; q < 4; ++q) {
                    xr[r][8*h + 2*q]     = __uint_as_float(wr[q] << 16);
                    xr[r][8*h + 2*q + 1] = __uint_as_float(wr[q] & 0xffff0000u);
                    xi[r][8*h + 2*q]     = __uint_as_float(wi[q] << 16);
                    xi[r][8*h + 2*q + 1] = __uint_as_float(wi[q] & 0xffff0000u);
                }
            }
        }
    }

    // --- preload even coeffs for step 0 ---
    float4 ec[8];
    {
        const float4* p = etab + 8 * lane;
        #pragma unroll
        for (int k = 0; k < 8; ++k) ec[k] = p[k];
    }

    for (int s = 0; s < NSTEP; ++s) {
        // prefetch odd coeffs for this step (covered by even-layer compute)
        float4 oc0 = otab[s * 512 + ((8 * lane + 511) & 511)];  // left boundary (lane0 -> identity)
        float4 oc[8];
        {
            const float4* p = otab + s * 512 + 8 * lane;        // lane63 k=7 -> identity
            #pragma unroll
            for (int k = 0; k < 8; ++k) oc[k] = p[k];
        }

        // ---- even layer: pair k -> local cols (2k, 2k+1) ----
        #pragma unroll
        for (int k = 0; k < 8; ++k) {
            float c = ec[k].x, sn = ec[k].y, sp = ec[k].z, cp = ec[k].w;
            #pragma unroll
            for (int r = 0; r < 2; ++r) {
                float ar = xr[r][2*k],   ai = xi[r][2*k];
                float br = xr[r][2*k+1], bi = xi[r][2*k+1];
                float tr = c*ar - sn*br;
                float ti = c*ai - sn*bi;
                xr[r][2*k]   = sp*tr - cp*ti;
                xi[r][2*k]   = sp*ti + cp*tr;
                xr[r][2*k+1] = c*br + sn*ar;
                xi[r][2*k+1] = c*bi + sn*ai;
            }
        }

        // prefetch next step's even coeffs (covered by odd-layer compute)
        if (s + 1 < NSTEP) {
            const float4* p = etab + (s + 1) * 512 + 8 * lane;
            #pragma unroll
            for (int k = 0; k < 8; ++k) ec[k] = p[k];
        }

        // ---- odd layer ----
        float xnr[2], xni[2], xlr[2], xli[2];
        #pragma unroll
        for (int r = 0; r < 2; ++r) {
            xnr[r] = __shfl_down(xr[r][0], 1, 64);   // right neighbor's col0 (old)
            xni[r] = __shfl_down(xi[r][0], 1, 64);
            xlr[r] = __shfl_up(xr[r][15], 1, 64);    // left neighbor's col15 (old)
            xli[r] = __shfl_up(xi[r][15], 1, 64);
        }
        // internal pairs: oc[k-1] -> local cols (2k-1, 2k), k=1..7
        #pragma unroll
        for (int k = 1; k < 8; ++k) {
            float c = oc[k-1].x, sn = oc[k-1].y, sp = oc[k-1].z, cp = oc[k-1].w;
            #pragma unroll
            for (int r = 0; r < 2; ++r) {
                float ar = xr[r][2*k-1], ai = xi[r][2*k-1];
                float br = xr[r][2*k],   bi = xi[r][2*k];
                float tr = c*ar - sn*br;
                float ti = c*ai - sn*bi;
                xr[r][2*k-1] = sp*tr - cp*ti;
                xi[r][2*k-1] = sp*ti + cp*tr;
                xr[r][2*k]   = c*br + sn*ar;
                xi[r][2*k]   = c*bi + sn*ai;
            }
        }
        // right boundary pair (our col15 = "a", neighbor col0 = "b"): update col15
        {
            float c = oc[7].x, sn = oc[7].y, sp = oc[7].z, cp = oc[7].w;
            #pragma unroll
            for (int r = 0; r < 2; ++r) {
                float ar = xr[r][15], ai = xi[r][15];
                float tr = c*ar - sn*xnr[r];
                float ti = c*ai - sn*xni[r];
                xr[r][15] = sp*tr - cp*ti;
                xi[r][15] = sp*ti + cp*tr;
            }
        }
        // left boundary pair (left col15 = "a", our col0 = "b"): update col0
        {
            float c = oc0.x, sn = oc0.y;
            #pragma unroll
            for (int r = 0; r < 2; ++r) {
                float br = xr[r][0], bi = xi[r][0];
                xr[r][0] = c*br + sn*xlr[r];
                xi[r][0] = c*bi + sn*xli[r];
            }
        }
    }

    // --- omega phase ---
    float ore[2][16], oim[2][16];
    const float4* wt4 = reinterpret_cast<const float4*>(wtab) + 8 * lane;
    #pragma unroll
    for (int r = 0; r < 2; ++r) {
        #pragma unroll
        for (int q = 0; q < 8; ++q) {
            float4 w2 = wt4[q];  // (cw0, sw0, cw1, sw1) for cols 2q, 2q+1
            ore[r][2*q]   = xr[r][2*q]   * w2.x - xi[r][2*q]   * w2.y;
            oim[r][2*q]   = xr[r][2*q]   * w2.y + xi[r][2*q]   * w2.x;
            ore[r][2*q+1] = xr[r][2*q+1] * w2.z - xi[r][2*q+1] * w2.w;
            oim[r][2*q+1] = xr[r][2*q+1] * w2.w + xi[r][2*q+1] * w2.z;
        }
    }

    // --- store in detected dtype ---
    if (isf32) {
        #pragma unroll
        for (int r = 0; r < 2; ++r) {
            float* pre = (float*)out + (row0 + r) * HDIM + colbase;
            float* pim = (float*)out + BDIM * HDIM + (row0 + r) * HDIM + colbase;
            #pragma unroll
            for (int q = 0; q < 4; ++q) {
                reinterpret_cast<float4*>(pre)[q] =
                    make_float4(ore[r][4*q], ore[r][4*q+1], ore[r][4*q+2], ore[r][4*q+3]);
                reinterpret_cast<float4*>(pim)[q] =
                    make_float4(oim[r][4*q], oim[r][4*q+1], oim[r][4*q+2], oim[r][4*q+3]);
            }
        }
    } else {
        #pragma unroll
        for (int r = 0; r < 2; ++r) {
            unsigned int wre[8], wim[8];
            #pragma unroll
            for (int q = 0; q < 8; ++q) {
                wre[q] = (unsigned int)f2bf(ore[r][2*q]) | ((unsigned int)f2bf(ore[r][2*q+1]) << 16);
                wim[q] = (unsigned int)f2bf(oim[r][2*q]) | ((unsigned int)f2bf(oim[r][2*q+1]) << 16);
            }
            unsigned short* pre = (unsigned short*)out + (row0 + r) * HDIM + colbase;
            unsigned short* pim = (unsigned short*)out + BDIM * HDIM + (row0 + r) * HDIM + colbase;
            reinterpret_cast<uint4*>(pre)[0] = make_uint4(wre[0], wre[1], wre[2], wre[3]);
            reinterpret_cast<uint4*>(pre)[1] = make_uint4(wre[4], wre[5], wre[6], wre[7]);
            reinterpret_cast<uint4*>(pim)[0] = make_uint4(wim[0], wim[1], wim[2], wim[3]);
            reinterpret_cast<uint4*>(pim)[1] = make_uint4(wim[4], wim[5], wim[6], wim[7]);
        }
    }
}

extern "C" void kernel_launch(void* const* d_in, const int* in_sizes, int n_in,
                              void* d_out, int out_size, void* d_ws, size_t ws_size,
                              hipStream_t stream)
{
    char* ws = (char*)d_ws;
    float4* etab = (float4*)ws;                             // 512 KB
    float4* otab = (float4*)(ws + NSTEP * 512 * 16);        // 512 KB
    float2* wtab = (float2*)(ws + 2 * NSTEP * 512 * 16);    // 8 KB
    int*    flag = (int*)(ws + 2 * NSTEP * 512 * 16 + HDIM * 8);

    detect_kernel<<<1, 64, 0, stream>>>((const unsigned short*)d_in[0], flag);
    coeff_kernel<<<260, 256, 0, stream>>>(d_in[2], d_in[3], d_in[4], d_in[5], d_in[6],
                                          etab, otab, wtab, flag);
    eunn_kernel<<<BDIM / 8, 256, 0, stream>>>(d_in[0], d_in[1], etab, otab, wtab,
                                              d_out, flag);
}